// Round 1
// baseline (517.858 us; speedup 1.0000x reference)
//
#include <hip/hip_runtime.h>

// Problem constants (from reference)
constexpr int LAYER_IDX = 5;
constexpr int WINDOW    = 13;
constexpr int B         = 8;
constexpr int L         = 6656;          // divisible by WINDOW
constexpr int D         = 1024;
constexpr int CH        = L / WINDOW;    // 512 groups per window row
constexpr int D4        = D / 4;         // float4 columns = 256

// Compare-exchange on 4 independent lanes (float4 components)
__device__ __forceinline__ void ce(float4& a, float4& b) {
    float4 lo, hi;
    lo.x = fminf(a.x, b.x); hi.x = fmaxf(a.x, b.x);
    lo.y = fminf(a.y, b.y); hi.y = fmaxf(a.y, b.y);
    lo.z = fminf(a.z, b.z); hi.z = fmaxf(a.z, b.z);
    lo.w = fminf(a.w, b.w); hi.w = fmaxf(a.w, b.w);
    a = lo; b = hi;
}

// One thread handles one (b, c, d4): gathers 13 float4 rows at stride CH*D,
// sorts the 13 values per component, scatters back to the same addresses.
// Block = 256 threads = all d4 for one (b, c)  ->  each of the 13 global
// accesses is one contiguous 4 KB row (perfectly coalesced).
__global__ __launch_bounds__(256)
void SWD16_sortwin_kernel(const float4* __restrict__ v, float4* __restrict__ out) {
    const int tid = blockIdx.x * blockDim.x + threadIdx.x;
    const int d4  = tid & (D4 - 1);          // D4 = 256
    const int bc  = tid >> 8;                // (b*CH + c)
    const int c   = bc & (CH - 1);           // CH = 512
    const int b   = bc >> 9;

    const float4* __restrict__ vb = v   + (size_t)b * (L * D4);
    float4*       __restrict__ ob = out + (size_t)b * (L * D4);

    float4 val[WINDOW];
    int    idx[WINDOW];

    #pragma unroll
    for (int w = 0; w < WINDOW; ++w) {
        int p = w * CH + c + LAYER_IDX;      // max 12*512+511+5 = 6660
        if (p >= L) p -= L;                  // wrap (only w=12, c>=507)
        idx[w] = p * D4 + d4;
        val[w] = vb[idx[w]];
    }

    // Odd-even transposition sort: 13 rounds, correct for n=13, branch-free.
    #pragma unroll
    for (int r = 0; r < WINDOW; ++r) {
        #pragma unroll
        for (int i = (r & 1); i + 1 < WINDOW; i += 2) {
            ce(val[i], val[i + 1]);
        }
    }

    #pragma unroll
    for (int w = 0; w < WINDOW; ++w) {
        ob[idx[w]] = val[w];
    }
}

extern "C" void kernel_launch(void* const* d_in, const int* in_sizes, int n_in,
                              void* d_out, int out_size, void* d_ws, size_t ws_size,
                              hipStream_t stream) {
    // inputs: d_in[0]=q (unused), d_in[1]=k (unused), d_in[2]=v (float32)
    const float4* v   = (const float4*)d_in[2];
    float4*       out = (float4*)d_out;

    const int total_threads = B * CH * D4;   // 1,048,576
    const int block = 256;
    const int grid  = total_threads / block; // 4096
    SWD16_sortwin_kernel<<<grid, block, 0, stream>>>(v, out);
}